// Round 5
// baseline (242.374 us; speedup 1.0000x reference)
//
#include <hip/hip_runtime.h>

typedef unsigned short u16;
typedef __attribute__((ext_vector_type(8))) short bf16x8;
typedef __attribute__((ext_vector_type(4))) float f32x4;
typedef __attribute__((ext_vector_type(4))) unsigned short u16x4;

#define MFMA16 __builtin_amdgcn_mfma_f32_16x16x32_bf16

__device__ inline u16 f2bf(float f) {            // cheap round-half-up
    union { float f; unsigned u; } v; v.f = f;
    return (u16)((v.u + 0x8000u) >> 16);
}

// async global->LDS, 16 B/lane. LDS dest = wave-uniform base + lane*16.
__device__ inline void gld16(const u16* g, u16* l) {
    __builtin_amdgcn_global_load_lds(
        (const __attribute__((address_space(1))) unsigned int*)g,
        (__attribute__((address_space(3))) unsigned int*)l, 16, 0, 0);
}

// ---------------- fp32 -> bf16 conversion + d_out zeroing ----------------
struct CvtArgs { const float* src[7]; u16* dst[7]; float* zero; };

__global__ __launch_bounds__(256) void cvt_kernel(CvtArgs a) {
    const int z = blockIdx.z;
    const size_t i = ((size_t)blockIdx.x * 256 + threadIdx.x) * 8;
    if (z == 7) {                     // zero d_out (4 M floats)
        float4 zz = {0.f, 0.f, 0.f, 0.f};
        *(float4*)(a.zero + i) = zz;
        *(float4*)(a.zero + i + 4) = zz;
        return;
    }
    const int n = (z < 3) ? 4194304 : 1048576;
    if (i >= (size_t)n) return;
    const float* s = a.src[z];
    float4 v0 = *(const float4*)(s + i);
    float4 v1 = *(const float4*)(s + i + 4);
    union { u16 h[8]; bf16x8 v; } o;
    o.h[0] = f2bf(v0.x); o.h[1] = f2bf(v0.y); o.h[2] = f2bf(v0.z); o.h[3] = f2bf(v0.w);
    o.h[4] = f2bf(v1.x); o.h[5] = f2bf(v1.y); o.h[6] = f2bf(v1.z); o.h[7] = f2bf(v1.w);
    *(bf16x8*)(a.dst[z] + i) = o.v;
}

// ---------------- QKV GEMM: 128x128 tile, BK=64 ----------------
struct GemmArgs { const u16* A; const u16* W; const float* bias; void* out; int epi; };
struct Gemm3Args { GemmArgs g[3]; };

__global__ __launch_bounds__(256, 3) void gemm_qkv(Gemm3Args ga) {
    __shared__ u16 lA[128 * 64];
    __shared__ u16 lB[128 * 64];
    const GemmArgs g = ga.g[blockIdx.z];
    const int t = threadIdx.x, wave = t >> 6, lane = t & 63;
    const int quad = lane >> 4, l16 = lane & 15;
    const int rowsA = blockIdx.y * 128, rowsB = blockIdx.x * 128;
    const int wm = (wave >> 1) * 64, wn = (wave & 1) * 64;
    const u16* A = g.A; const u16* W = g.W;

    f32x4 acc[4][4] = {};

    for (int kb = 0; kb < 1024; kb += 64) {
#pragma unroll
        for (int i = 0; i < 4; i++) {
            int u = (i * 4 + wave) * 64 + lane;
            int row = u >> 3, cu = (u & 7) ^ (row & 7);
            gld16(A + (size_t)(rowsA + row) * 1024 + kb + cu * 8, lA + u * 8);
        }
#pragma unroll
        for (int i = 0; i < 4; i++) {
            int u = (i * 4 + wave) * 64 + lane;
            int row = u >> 3, cu = (u & 7) ^ (row & 7);
            gld16(W + (size_t)(rowsB + row) * 1024 + kb + cu * 8, lB + u * 8);
        }
        __syncthreads();

        bf16x8 af[4][2], bfr[4][2];
#pragma unroll
        for (int mi = 0; mi < 4; mi++) {
            int row = wm + mi * 16 + l16;
#pragma unroll
            for (int kr = 0; kr < 2; kr++)
                af[mi][kr] = *(const bf16x8*)(lA + row * 64 + (((kr * 4 + quad) ^ (row & 7)) * 8));
        }
#pragma unroll
        for (int ni = 0; ni < 4; ni++) {
            int row = wn + ni * 16 + l16;
#pragma unroll
            for (int kr = 0; kr < 2; kr++)
                bfr[ni][kr] = *(const bf16x8*)(lB + row * 64 + (((kr * 4 + quad) ^ (row & 7)) * 8));
        }
#pragma unroll
        for (int mi = 0; mi < 4; mi++)
#pragma unroll
            for (int ni = 0; ni < 4; ni++) {
                acc[mi][ni] = MFMA16(af[mi][0], bfr[ni][0], acc[mi][ni], 0, 0, 0);
                acc[mi][ni] = MFMA16(af[mi][1], bfr[ni][1], acc[mi][ni], 0, 0, 0);
            }
        __syncthreads();
    }

    const int epi = g.epi;
#pragma unroll
    for (int ni = 0; ni < 4; ni++) {
        const int ncol = rowsB + wn + ni * 16 + l16;
        const float bv = g.bias[ncol];
        const int h = ncol >> 6, hd = ncol & 63;
#pragma unroll
        for (int mi = 0; mi < 4; mi++) {
            const int mrow0 = rowsA + wm + mi * 16 + quad * 4;
            const int b = mrow0 >> 10, l0 = mrow0 & 1023;
            if (epi == 0) {
#pragma unroll
                for (int r = 0; r < 4; r++)
                    ((u16*)g.out)[((size_t)(b * 16 + h) * 1024 + l0 + r) * 64 + hd] =
                        f2bf(acc[mi][ni][r] + bv);
            } else {
                u16x4 pk;
#pragma unroll
                for (int r = 0; r < 4; r++) pk[r] = f2bf(acc[mi][ni][r] + bv);
                *(u16x4*)((u16*)g.out + ((size_t)(b * 16 + h) * 64 + hd) * 1024 + l0) = pk;
            }
        }
    }
}

// ---------------- P GEMM: 128x128 tile, BK=64, split-K=2, atomic fp32 out ----------------
__global__ __launch_bounds__(256, 3) void gemm_p(const u16* __restrict__ A,
                                                 const u16* __restrict__ W,
                                                 const float* __restrict__ bias,
                                                 float* __restrict__ out)
{
    __shared__ u16 lA[128 * 64];
    __shared__ u16 lB[128 * 64];
    const int t = threadIdx.x, wave = t >> 6, lane = t & 63;
    const int quad = lane >> 4, l16 = lane & 15;
    const int rowsA = blockIdx.y * 128, rowsB = blockIdx.x * 128;
    const int wm = (wave >> 1) * 64, wn = (wave & 1) * 64;
    const int k0 = blockIdx.z * 512;

    f32x4 acc[4][4] = {};

    for (int kb = k0; kb < k0 + 512; kb += 64) {
#pragma unroll
        for (int i = 0; i < 4; i++) {
            int u = (i * 4 + wave) * 64 + lane;
            int row = u >> 3, cu = (u & 7) ^ (row & 7);
            gld16(A + (size_t)(rowsA + row) * 1024 + kb + cu * 8, lA + u * 8);
        }
#pragma unroll
        for (int i = 0; i < 4; i++) {
            int u = (i * 4 + wave) * 64 + lane;
            int row = u >> 3, cu = (u & 7) ^ (row & 7);
            gld16(W + (size_t)(rowsB + row) * 1024 + kb + cu * 8, lB + u * 8);
        }
        __syncthreads();

        bf16x8 af[4][2], bfr[4][2];
#pragma unroll
        for (int mi = 0; mi < 4; mi++) {
            int row = wm + mi * 16 + l16;
#pragma unroll
            for (int kr = 0; kr < 2; kr++)
                af[mi][kr] = *(const bf16x8*)(lA + row * 64 + (((kr * 4 + quad) ^ (row & 7)) * 8));
        }
#pragma unroll
        for (int ni = 0; ni < 4; ni++) {
            int row = wn + ni * 16 + l16;
#pragma unroll
            for (int kr = 0; kr < 2; kr++)
                bfr[ni][kr] = *(const bf16x8*)(lB + row * 64 + (((kr * 4 + quad) ^ (row & 7)) * 8));
        }
#pragma unroll
        for (int mi = 0; mi < 4; mi++)
#pragma unroll
            for (int ni = 0; ni < 4; ni++) {
                acc[mi][ni] = MFMA16(af[mi][0], bfr[ni][0], acc[mi][ni], 0, 0, 0);
                acc[mi][ni] = MFMA16(af[mi][1], bfr[ni][1], acc[mi][ni], 0, 0, 0);
            }
        __syncthreads();
    }

    const bool addb = (blockIdx.z == 0);
#pragma unroll
    for (int ni = 0; ni < 4; ni++) {
        const int ncol = rowsB + wn + ni * 16 + l16;
        const float bv = addb ? bias[ncol] : 0.f;
#pragma unroll
        for (int mi = 0; mi < 4; mi++) {
            const int mrow0 = rowsA + wm + mi * 16 + quad * 4;
#pragma unroll
            for (int r = 0; r < 4; r++)
                atomicAdd(&out[(size_t)(mrow0 + r) * 1024 + ncol], acc[mi][ni][r] + bv);
        }
    }
}

// ---------------- flash attention, 128-row q-tiles, no online max ----------------
// grid (8 qtiles longest-first, 64 heads); block 256 = 4 waves; 32 q-rows/wave.
__global__ __launch_bounds__(256, 3) void attn_kernel(const u16* __restrict__ qh,
                                                      const u16* __restrict__ kh,
                                                      const u16* __restrict__ vhT,
                                                      u16* __restrict__ y)
{
    __shared__ u16 sK[64 * 64];
    __shared__ u16 sVT[64 * 64];
    __shared__ u16 sP[4 * 32 * 72];

    const int t = threadIdx.x, wave = t >> 6, lane = t & 63;
    const int quad = lane >> 4, l16 = lane & 15;
    const int qt = 7 - blockIdx.x, bh = blockIdx.y;
    const size_t base = (size_t)bh * 1024 * 64;
    const int qoff = qt * 128 + wave * 32;
    const float e2 = 0.18033688f;     // 0.125 * log2(e)

    bf16x8 aq[2][2];
#pragma unroll
    for (int qf = 0; qf < 2; qf++)
#pragma unroll
        for (int kr = 0; kr < 2; kr++)
            aq[qf][kr] = *(const bf16x8*)(qh + base + (size_t)(qoff + qf * 16 + l16) * 64 + kr * 32 + quad * 8);

    bf16x8 ones;
#pragma unroll
    for (int j = 0; j < 8; j++) ones[j] = (short)0x3F80;

    f32x4 o[2][4] = {};
    f32x4 lacc[2] = {};
    u16* pw = sP + wave * 32 * 72;

    const int nkb = 2 * qt + 2;
    for (int kb = 0; kb < nkb; kb++) {
        const int krow0 = kb * 64;
#pragma unroll
        for (int i = 0; i < 2; i++) {
            int u = (i * 4 + wave) * 64 + lane;
            int row = u >> 3, cu = (u & 7) ^ (row & 7);
            gld16(kh + base + (size_t)(krow0 + row) * 64 + cu * 8, sK + u * 8);
        }
#pragma unroll
        for (int i = 0; i < 2; i++) {
            int u = (i * 4 + wave) * 64 + lane;
            int row = u >> 3, cu = (u & 7) ^ (row & 7);
            gld16(vhT + ((size_t)(bh * 64 + row)) * 1024 + krow0 + cu * 8, sVT + u * 8);
        }
        __syncthreads();

        bf16x8 bk[4][2];
#pragma unroll
        for (int kc = 0; kc < 4; kc++) {
            int row = kc * 16 + l16;
#pragma unroll
            for (int kr = 0; kr < 2; kr++)
                bk[kc][kr] = *(const bf16x8*)(sK + row * 64 + (((kr * 4 + quad) ^ (row & 7)) * 8));
        }

        f32x4 sc[2][4];
        bool act[2];
#pragma unroll
        for (int qf = 0; qf < 2; qf++) {
            const int qbase = qoff + qf * 16;
            act[qf] = (krow0 <= qbase + 15);
            if (act[qf]) {
#pragma unroll
                for (int kc = 0; kc < 4; kc++) {
                    f32x4 z = {};
                    z = MFMA16(aq[qf][0], bk[kc][0], z, 0, 0, 0);
                    z = MFMA16(aq[qf][1], bk[kc][1], z, 0, 0, 0);
                    sc[qf][kc] = z;
                }
            }
        }
#pragma unroll
        for (int qf = 0; qf < 2; qf++) {
            if (!act[qf]) continue;
            const int qbase = qoff + qf * 16;
            const bool dm = (krow0 + 63 > qbase);
#pragma unroll
            for (int kc = 0; kc < 4; kc++)
#pragma unroll
                for (int r = 0; r < 4; r++) {
                    float x = fminf(sc[qf][kc][r] * e2, 43.f);
                    float pv = exp2f(x);
                    if (dm) {
                        int kcol = krow0 + kc * 16 + l16;
                        int qrow = qbase + quad * 4 + r;
                        if (kcol > qrow) pv = 0.f;
                    }
                    pw[(qf * 16 + quad * 4 + r) * 72 + kc * 16 + l16] = f2bf(pv);
                }
        }

        bf16x8 bv[4][2];
#pragma unroll
        for (int nt = 0; nt < 4; nt++) {
            int row = nt * 16 + l16;
#pragma unroll
            for (int kr = 0; kr < 2; kr++)
                bv[nt][kr] = *(const bf16x8*)(sVT + row * 64 + (((kr * 4 + quad) ^ (row & 7)) * 8));
        }
#pragma unroll
        for (int qf = 0; qf < 2; qf++) {
            if (!act[qf]) continue;
            bf16x8 ap0 = *(const bf16x8*)(pw + (qf * 16 + l16) * 72 + quad * 8);
            bf16x8 ap1 = *(const bf16x8*)(pw + (qf * 16 + l16) * 72 + 32 + quad * 8);
#pragma unroll
            for (int nt = 0; nt < 4; nt++) {
                o[qf][nt] = MFMA16(ap0, bv[nt][0], o[qf][nt], 0, 0, 0);
                o[qf][nt] = MFMA16(ap1, bv[nt][1], o[qf][nt], 0, 0, 0);
            }
            lacc[qf] = MFMA16(ap0, ones, lacc[qf], 0, 0, 0);
            lacc[qf] = MFMA16(ap1, ones, lacc[qf], 0, 0, 0);
        }
        __syncthreads();
    }

    const int b = bh >> 4, h = bh & 15;
#pragma unroll
    for (int qf = 0; qf < 2; qf++)
#pragma unroll
        for (int nt = 0; nt < 4; nt++)
#pragma unroll
            for (int r = 0; r < 4; r++) {
                int qrow = qoff + qf * 16 + quad * 4 + r;
                int d = nt * 16 + l16;
                y[(size_t)(b * 1024 + qrow) * 1024 + h * 64 + d] =
                    f2bf(o[qf][nt][r] / lacc[qf][r]);
            }
}

extern "C" void kernel_launch(void* const* d_in, const int* in_sizes, int n_in,
                              void* d_out, int out_size, void* d_ws, size_t ws_size,
                              hipStream_t stream)
{
    const float* key   = (const float*)d_in[0];
    const float* value = (const float*)d_in[1];
    const float* query = (const float*)d_in[2];
    const float* Wk = (const float*)d_in[3];
    const float* bk = (const float*)d_in[4];
    const float* Wq = (const float*)d_in[5];
    const float* bq = (const float*)d_in[6];
    const float* Wv = (const float*)d_in[7];
    const float* bv = (const float*)d_in[8];
    const float* Wp = (const float*)d_in[9];
    const float* bp = (const float*)d_in[10];

    char* ws = (char*)d_ws;
    u16* xq  = (u16*)(ws + (size_t)( 0 << 20));
    u16* xk  = (u16*)(ws + (size_t)( 8 << 20));
    u16* xv  = (u16*)(ws + (size_t)(16 << 20));
    u16* wqb = (u16*)(ws + (size_t)(24 << 20));
    u16* wkb = (u16*)(ws + (size_t)(26 << 20));
    u16* wvb = (u16*)(ws + (size_t)(28 << 20));
    u16* wpb = (u16*)(ws + (size_t)(30 << 20));
    u16* qh  = (u16*)(ws + (size_t)(32 << 20));
    u16* kh  = (u16*)(ws + (size_t)(40 << 20));
    u16* vhT = (u16*)(ws + (size_t)(48 << 20));
    u16* y   = xq;   // xq dead after QKV GEMM

    CvtArgs ca;
    ca.src[0] = query; ca.dst[0] = xq;
    ca.src[1] = key;   ca.dst[1] = xk;
    ca.src[2] = value; ca.dst[2] = xv;
    ca.src[3] = Wq;    ca.dst[3] = wqb;
    ca.src[4] = Wk;    ca.dst[4] = wkb;
    ca.src[5] = Wv;    ca.dst[5] = wvb;
    ca.src[6] = Wp;    ca.dst[6] = wpb;
    ca.zero = (float*)d_out;
    hipLaunchKernelGGL(cvt_kernel, dim3(2048, 1, 8), dim3(256), 0, stream, ca);

    Gemm3Args g3;
    g3.g[0] = GemmArgs{xq, wqb, bq, (void*)qh,  0};
    g3.g[1] = GemmArgs{xk, wkb, bk, (void*)kh,  0};
    g3.g[2] = GemmArgs{xv, wvb, bv, (void*)vhT, 2};
    hipLaunchKernelGGL(gemm_qkv, dim3(8, 32, 3), dim3(256), 0, stream, g3);

    hipLaunchKernelGGL(attn_kernel, dim3(8, 64), dim3(256), 0, stream, qh, kh, vhT, y);

    hipLaunchKernelGGL(gemm_p, dim3(8, 32, 2), dim3(256), 0, stream, y, wpb, bp, (float*)d_out);
}

// Round 6
// 197.004 us; speedup vs baseline: 1.2303x; 1.2303x over previous
//
#include <hip/hip_runtime.h>

typedef unsigned short u16;
typedef __attribute__((ext_vector_type(8))) short bf16x8;
typedef __attribute__((ext_vector_type(4))) float f32x4;
typedef __attribute__((ext_vector_type(4))) unsigned short u16x4;

#define MFMA16 __builtin_amdgcn_mfma_f32_16x16x32_bf16

__device__ inline u16 f2bf(float f) {            // cheap round-half-up
    union { float f; unsigned u; } v; v.f = f;
    return (u16)((v.u + 0x8000u) >> 16);
}

// async global->LDS, 16 B/lane. LDS dest = wave-uniform base + lane*16.
__device__ inline void gld16(const u16* g, u16* l) {
    __builtin_amdgcn_global_load_lds(
        (const __attribute__((address_space(1))) unsigned int*)g,
        (__attribute__((address_space(3))) unsigned int*)l, 16, 0, 0);
}

// ---------------- fp32 -> bf16 conversion ----------------
struct CvtArgs { const float* src[7]; u16* dst[7]; };

__global__ __launch_bounds__(256) void cvt_kernel(CvtArgs a) {
    const int z = blockIdx.z;
    const int n = (z < 3) ? 4194304 : 1048576;
    const size_t i = ((size_t)blockIdx.x * 256 + threadIdx.x) * 8;
    if (i >= (size_t)n) return;
    const float* s = a.src[z];
    float4 v0 = *(const float4*)(s + i);
    float4 v1 = *(const float4*)(s + i + 4);
    union { u16 h[8]; bf16x8 v; } o;
    o.h[0] = f2bf(v0.x); o.h[1] = f2bf(v0.y); o.h[2] = f2bf(v0.z); o.h[3] = f2bf(v0.w);
    o.h[4] = f2bf(v1.x); o.h[5] = f2bf(v1.y); o.h[6] = f2bf(v1.z); o.h[7] = f2bf(v1.w);
    *(bf16x8*)(a.dst[z] + i) = o.v;
}

// ---------------- QKV GEMM: 128x128 tile, BK=64, XCD-swizzled ----------------
struct GemmArgs { const u16* A; const u16* W; const float* bias; void* out; int epi; };
struct Gemm3Args { GemmArgs g[3]; };

__global__ __launch_bounds__(256, 3) void gemm_qkv(Gemm3Args ga) {
    __shared__ u16 lA[128 * 64];
    __shared__ u16 lB[128 * 64];
    const GemmArgs g = ga.g[blockIdx.z];
    const int t = threadIdx.x, wave = t >> 6, lane = t & 63;
    const int quad = lane >> 4, l16 = lane & 15;
    // XCD swizzle: xcd = bid&7 owns mtiles [xcd*4, xcd*4+4) x all 8 ntiles
    const int bid = blockIdx.x;
    const int mtile = (bid & 7) * 4 + (bid >> 6);
    const int ntile = (bid >> 3) & 7;
    const int rowsA = mtile * 128, rowsB = ntile * 128;
    const int wm = (wave >> 1) * 64, wn = (wave & 1) * 64;
    const u16* A = g.A; const u16* W = g.W;

    f32x4 acc[4][4] = {};

    for (int kb = 0; kb < 1024; kb += 64) {
#pragma unroll
        for (int i = 0; i < 4; i++) {
            int u = (i * 4 + wave) * 64 + lane;
            int row = u >> 3, cu = (u & 7) ^ (row & 7);
            gld16(A + (size_t)(rowsA + row) * 1024 + kb + cu * 8, lA + u * 8);
        }
#pragma unroll
        for (int i = 0; i < 4; i++) {
            int u = (i * 4 + wave) * 64 + lane;
            int row = u >> 3, cu = (u & 7) ^ (row & 7);
            gld16(W + (size_t)(rowsB + row) * 1024 + kb + cu * 8, lB + u * 8);
        }
        __syncthreads();

        bf16x8 af[4][2], bfr[4][2];
#pragma unroll
        for (int mi = 0; mi < 4; mi++) {
            int row = wm + mi * 16 + l16;
#pragma unroll
            for (int kr = 0; kr < 2; kr++)
                af[mi][kr] = *(const bf16x8*)(lA + row * 64 + (((kr * 4 + quad) ^ (row & 7)) * 8));
        }
#pragma unroll
        for (int ni = 0; ni < 4; ni++) {
            int row = wn + ni * 16 + l16;
#pragma unroll
            for (int kr = 0; kr < 2; kr++)
                bfr[ni][kr] = *(const bf16x8*)(lB + row * 64 + (((kr * 4 + quad) ^ (row & 7)) * 8));
        }
#pragma unroll
        for (int mi = 0; mi < 4; mi++)
#pragma unroll
            for (int ni = 0; ni < 4; ni++) {
                acc[mi][ni] = MFMA16(af[mi][0], bfr[ni][0], acc[mi][ni], 0, 0, 0);
                acc[mi][ni] = MFMA16(af[mi][1], bfr[ni][1], acc[mi][ni], 0, 0, 0);
            }
        __syncthreads();
    }

    const int epi = g.epi;
#pragma unroll
    for (int ni = 0; ni < 4; ni++) {
        const int ncol = rowsB + wn + ni * 16 + l16;
        const float bv = g.bias[ncol];
        const int h = ncol >> 6, hd = ncol & 63;
#pragma unroll
        for (int mi = 0; mi < 4; mi++) {
            const int mrow0 = rowsA + wm + mi * 16 + quad * 4;
            const int b = mrow0 >> 10, l0 = mrow0 & 1023;
            if (epi == 0) {
#pragma unroll
                for (int r = 0; r < 4; r++)
                    ((u16*)g.out)[((size_t)(b * 16 + h) * 1024 + l0 + r) * 64 + hd] =
                        f2bf(acc[mi][ni][r] + bv);
            } else {
                u16x4 pk;
#pragma unroll
                for (int r = 0; r < 4; r++) pk[r] = f2bf(acc[mi][ni][r] + bv);
                *(u16x4*)((u16*)g.out + ((size_t)(b * 16 + h) * 64 + hd) * 1024 + l0) = pk;
            }
        }
    }
}

// ---------------- P GEMM: 128x64 tile, BK=64, fp32 out, XCD-swizzled ----------------
__global__ __launch_bounds__(256, 2) void gemm_p(const u16* __restrict__ A,
                                                 const u16* __restrict__ W,
                                                 const float* __restrict__ bias,
                                                 float* __restrict__ out)
{
    __shared__ u16 lA[128 * 64];
    __shared__ u16 lB[64 * 64];
    const int t = threadIdx.x, wave = t >> 6, lane = t & 63;
    const int quad = lane >> 4, l16 = lane & 15;
    // XCD swizzle: xcd = bid&7 owns mtiles [xcd*4, xcd*4+4) x all 16 ntiles
    const int bid = blockIdx.x;
    const int mtile = (bid & 7) * 4 + (bid >> 7);
    const int ntile = (bid >> 3) & 15;
    const int rowsA = mtile * 128, rowsB = ntile * 64;
    const int wm = (wave >> 1) * 64, wn = (wave & 1) * 32;

    f32x4 acc[4][2] = {};

    for (int kb = 0; kb < 1024; kb += 64) {
#pragma unroll
        for (int i = 0; i < 4; i++) {
            int u = (i * 4 + wave) * 64 + lane;
            int row = u >> 3, cu = (u & 7) ^ (row & 7);
            gld16(A + (size_t)(rowsA + row) * 1024 + kb + cu * 8, lA + u * 8);
        }
#pragma unroll
        for (int i = 0; i < 2; i++) {
            int u = (i * 4 + wave) * 64 + lane;
            int row = u >> 3, cu = (u & 7) ^ (row & 7);
            gld16(W + (size_t)(rowsB + row) * 1024 + kb + cu * 8, lB + u * 8);
        }
        __syncthreads();

        bf16x8 af[4][2], bfr[2][2];
#pragma unroll
        for (int mi = 0; mi < 4; mi++) {
            int row = wm + mi * 16 + l16;
#pragma unroll
            for (int kr = 0; kr < 2; kr++)
                af[mi][kr] = *(const bf16x8*)(lA + row * 64 + (((kr * 4 + quad) ^ (row & 7)) * 8));
        }
#pragma unroll
        for (int ni = 0; ni < 2; ni++) {
            int row = wn + ni * 16 + l16;
#pragma unroll
            for (int kr = 0; kr < 2; kr++)
                bfr[ni][kr] = *(const bf16x8*)(lB + row * 64 + (((kr * 4 + quad) ^ (row & 7)) * 8));
        }
#pragma unroll
        for (int mi = 0; mi < 4; mi++)
#pragma unroll
            for (int ni = 0; ni < 2; ni++) {
                acc[mi][ni] = MFMA16(af[mi][0], bfr[ni][0], acc[mi][ni], 0, 0, 0);
                acc[mi][ni] = MFMA16(af[mi][1], bfr[ni][1], acc[mi][ni], 0, 0, 0);
            }
        __syncthreads();
    }

#pragma unroll
    for (int ni = 0; ni < 2; ni++) {
        const int ncol = rowsB + wn + ni * 16 + l16;
        const float bv = bias[ncol];
#pragma unroll
        for (int mi = 0; mi < 4; mi++) {
            const int mrow0 = rowsA + wm + mi * 16 + quad * 4;
#pragma unroll
            for (int r = 0; r < 4; r++)
                out[(size_t)(mrow0 + r) * 1024 + ncol] = acc[mi][ni][r] + bv;
        }
    }
}

// ---------------- flash attention: 16 q-rows/wave, paired 32-row chunks ----------------
// grid (16 pairs, 64 heads) = 1024 blocks -> 4 blocks/CU, 16 waves/CU.
// Block p: waves 0-1 -> chunk 31-p (rows [(31-p)*32, +32)), waves 2-3 -> chunk p.
// Compute per block balanced (~17 tile-passes); no online max (exp-sum via MFMA ones).
__global__ __launch_bounds__(256, 4) void attn_kernel(const u16* __restrict__ qh,
                                                      const u16* __restrict__ kh,
                                                      const u16* __restrict__ vhT,
                                                      u16* __restrict__ y)
{
    __shared__ u16 sK[64 * 64];
    __shared__ u16 sVT[64 * 64];
    __shared__ u16 sP[4 * 16 * 72];

    const int t = threadIdx.x, wave = t >> 6, lane = t & 63;
    const int quad = lane >> 4, l16 = lane & 15;
    const int p = blockIdx.x, bh = blockIdx.y;
    const int c_l = 31 - p;
    const int chunk = (wave < 2) ? c_l : p;
    const int qbase = chunk * 32 + (wave & 1) * 16;   // this wave's 16 q rows
    const size_t base = (size_t)bh * 1024 * 64;
    const float e2 = 0.18033688f;                      // 0.125 * log2(e)

    bf16x8 aq[2];
#pragma unroll
    for (int kr = 0; kr < 2; kr++)
        aq[kr] = *(const bf16x8*)(qh + base + (size_t)(qbase + l16) * 64 + kr * 32 + quad * 8);

    bf16x8 ones;
#pragma unroll
    for (int j = 0; j < 8; j++) ones[j] = (short)0x3F80;

    f32x4 o[4] = {};
    f32x4 lacc = {};
    u16* pw = sP + wave * 16 * 72;

    const int nkb = (c_l + 2) >> 1;    // tiles covering rows [0, (c_l+1)*32)
    for (int kb = 0; kb < nkb; kb++) {
        const int krow0 = kb * 64;
#pragma unroll
        for (int i = 0; i < 2; i++) {
            int u = (i * 4 + wave) * 64 + lane;
            int row = u >> 3, cu = (u & 7) ^ (row & 7);
            gld16(kh + base + (size_t)(krow0 + row) * 64 + cu * 8, sK + u * 8);
        }
#pragma unroll
        for (int i = 0; i < 2; i++) {
            int u = (i * 4 + wave) * 64 + lane;
            int row = u >> 3, cu = (u & 7) ^ (row & 7);
            gld16(vhT + ((size_t)(bh * 64 + row)) * 1024 + krow0 + cu * 8, sVT + u * 8);
        }
        __syncthreads();

        if (krow0 <= qbase + 15) {
            bf16x8 bk[4][2];
#pragma unroll
            for (int kc = 0; kc < 4; kc++) {
                int row = kc * 16 + l16;
#pragma unroll
                for (int kr = 0; kr < 2; kr++)
                    bk[kc][kr] = *(const bf16x8*)(sK + row * 64 + (((kr * 4 + quad) ^ (row & 7)) * 8));
            }
            f32x4 sc[4];
#pragma unroll
            for (int kc = 0; kc < 4; kc++) {
                f32x4 z = {};
                z = MFMA16(aq[0], bk[kc][0], z, 0, 0, 0);
                z = MFMA16(aq[1], bk[kc][1], z, 0, 0, 0);
                sc[kc] = z;
            }
            const bool dm = (krow0 + 63 > qbase);
#pragma unroll
            for (int kc = 0; kc < 4; kc++)
#pragma unroll
                for (int r = 0; r < 4; r++) {
                    float x = fminf(sc[kc][r] * e2, 43.f);
                    float pv = exp2f(x);
                    if (dm) {
                        int kcol = krow0 + kc * 16 + l16;
                        int qrow = qbase + quad * 4 + r;
                        if (kcol > qrow) pv = 0.f;
                    }
                    pw[(quad * 4 + r) * 72 + kc * 16 + l16] = f2bf(pv);
                }
            bf16x8 bv[4][2];
#pragma unroll
            for (int nt = 0; nt < 4; nt++) {
                int row = nt * 16 + l16;
#pragma unroll
                for (int kr = 0; kr < 2; kr++)
                    bv[nt][kr] = *(const bf16x8*)(sVT + row * 64 + (((kr * 4 + quad) ^ (row & 7)) * 8));
            }
            bf16x8 ap0 = *(const bf16x8*)(pw + l16 * 72 + quad * 8);
            bf16x8 ap1 = *(const bf16x8*)(pw + l16 * 72 + 32 + quad * 8);
#pragma unroll
            for (int nt = 0; nt < 4; nt++) {
                o[nt] = MFMA16(ap0, bv[nt][0], o[nt], 0, 0, 0);
                o[nt] = MFMA16(ap1, bv[nt][1], o[nt], 0, 0, 0);
            }
            lacc = MFMA16(ap0, ones, lacc, 0, 0, 0);
            lacc = MFMA16(ap1, ones, lacc, 0, 0, 0);
        }
        __syncthreads();
    }

    const int b = bh >> 4, h = bh & 15;
#pragma unroll
    for (int nt = 0; nt < 4; nt++)
#pragma unroll
        for (int r = 0; r < 4; r++) {
            int qrow = qbase + quad * 4 + r;
            int d = nt * 16 + l16;
            y[(size_t)(b * 1024 + qrow) * 1024 + h * 64 + d] = f2bf(o[nt][r] / lacc[r]);
        }
}

extern "C" void kernel_launch(void* const* d_in, const int* in_sizes, int n_in,
                              void* d_out, int out_size, void* d_ws, size_t ws_size,
                              hipStream_t stream)
{
    const float* key   = (const float*)d_in[0];
    const float* value = (const float*)d_in[1];
    const float* query = (const float*)d_in[2];
    const float* Wk = (const float*)d_in[3];
    const float* bk = (const float*)d_in[4];
    const float* Wq = (const float*)d_in[5];
    const float* bq = (const float*)d_in[6];
    const float* Wv = (const float*)d_in[7];
    const float* bv = (const float*)d_in[8];
    const float* Wp = (const float*)d_in[9];
    const float* bp = (const float*)d_in[10];

    char* ws = (char*)d_ws;
    u16* xq  = (u16*)(ws + (size_t)( 0 << 20));
    u16* xk  = (u16*)(ws + (size_t)( 8 << 20));
    u16* xv  = (u16*)(ws + (size_t)(16 << 20));
    u16* wqb = (u16*)(ws + (size_t)(24 << 20));
    u16* wkb = (u16*)(ws + (size_t)(26 << 20));
    u16* wvb = (u16*)(ws + (size_t)(28 << 20));
    u16* wpb = (u16*)(ws + (size_t)(30 << 20));
    u16* qh  = (u16*)(ws + (size_t)(32 << 20));
    u16* kh  = (u16*)(ws + (size_t)(40 << 20));
    u16* vhT = (u16*)(ws + (size_t)(48 << 20));
    u16* y   = xq;   // xq dead after QKV GEMM

    CvtArgs ca;
    ca.src[0] = query; ca.dst[0] = xq;
    ca.src[1] = key;   ca.dst[1] = xk;
    ca.src[2] = value; ca.dst[2] = xv;
    ca.src[3] = Wq;    ca.dst[3] = wqb;
    ca.src[4] = Wk;    ca.dst[4] = wkb;
    ca.src[5] = Wv;    ca.dst[5] = wvb;
    ca.src[6] = Wp;    ca.dst[6] = wpb;
    hipLaunchKernelGGL(cvt_kernel, dim3(2048, 1, 7), dim3(256), 0, stream, ca);

    Gemm3Args g3;
    g3.g[0] = GemmArgs{xq, wqb, bq, (void*)qh,  0};
    g3.g[1] = GemmArgs{xk, wkb, bk, (void*)kh,  0};
    g3.g[2] = GemmArgs{xv, wvb, bv, (void*)vhT, 2};
    hipLaunchKernelGGL(gemm_qkv, dim3(256, 1, 3), dim3(256), 0, stream, g3);

    hipLaunchKernelGGL(attn_kernel, dim3(16, 64), dim3(256), 0, stream, qh, kh, vhT, y);

    hipLaunchKernelGGL(gemm_p, dim3(512), dim3(256), 0, stream, y, wpb, bp, (float*)d_out);
}